// Round 12
// baseline (2587.894 us; speedup 1.0000x reference)
//
#include <hip/hip_runtime.h>
#include <hip/hip_bf16.h>

#define Tn 64
#define NB 8
#define NTH 1024

typedef unsigned int u32;
typedef _Float16 h2 __attribute__((ext_vector_type(2)));
typedef __fp16 fp16x2 __attribute__((ext_vector_type(2)));
typedef short s16x8 __attribute__((ext_vector_type(8)));
typedef float f32x4 __attribute__((ext_vector_type(4)));

#define MFMA16(a, b, c) __builtin_amdgcn_mfma_f32_16x16x32_bf16(a, b, c, 0, 0, 0)

__device__ __forceinline__ h2 as_h2(u32 u) { union { u32 u; h2 h; } c; c.u = u; return c.h; }

__device__ __forceinline__ float dot2h(u32 a, u32 w, float acc) {
  return __builtin_amdgcn_fdot2(as_h2(a), as_h2(w), acc, false);
}

__device__ __forceinline__ u32 pkh(float a, float b) {
  union { u32 u; fp16x2 h; } c;
  c.h = __builtin_amdgcn_cvt_pkrtz(a, b);
  return c.u;
}

__device__ __forceinline__ unsigned short bfq(float x) {
  u32 u = __float_as_uint(x);
  return (unsigned short)((u + 0x7fffu + ((u >> 16) & 1)) >> 16);
}

__device__ __forceinline__ u32 pack2bf(float a, float b) {
  u32 ua = __float_as_uint(a), ub = __float_as_uint(b);
  ua = (ua + 0x7fffu + ((ua >> 16) & 1)) >> 16;
  ub = (ub + 0x7fffu + ((ub >> 16) & 1)) >> 16;
  return (ua & 0xffffu) | (ub << 16);
}

// non-temporal float2 load (streaming: don't pollute L2)
__device__ __forceinline__ float2 ntload2(const float* p) {
  double d = __builtin_nontemporal_load((const double*)p);
  union { double d; float2 f; } c; c.d = d;
  return c.f;
}

#define FEXP(x) __builtin_amdgcn_exp2f(x)
#define CE 2.885390081777927f /* 2*log2(e) */

__device__ __forceinline__ float fast_rcp(float x) { return __builtin_amdgcn_rcpf(x); }
__device__ __forceinline__ float fast_tanh(float x) {
  float e = __expf(2.f * x);
  return 1.f - 2.f * fast_rcp(1.f + e);
}
__device__ __forceinline__ float fast_sig(float x) {
  return fast_rcp(1.f + __expf(-x));
}

// ---------------- weight pre-pack (unchanged layouts) ----------------
__global__ void pack_weights(const float* __restrict__ W_d_w,
                             const float* __restrict__ W_hh,
                             const float* __restrict__ W_dec_w,
                             const float* __restrict__ W_y_w,
                             const float* __restrict__ U_d_w,
                             const float* __restrict__ w_tilda_w,
                             short* __restrict__ WdP, short* __restrict__ WhhP,
                             short* __restrict__ WdecP, u32* __restrict__ UdP,
                             u32* __restrict__ wtP, u32* __restrict__ WyP2) {
  const int i0 = blockIdx.x * blockDim.x + threadIdx.x;
  const int stride = gridDim.x * blockDim.x;
  for (int i = i0; i < 32768; i += stride) {  // WdP
    int e = i & 7, lane = (i >> 3) & 63, w = (i >> 9) & 7, kk = i >> 12;
    int n = w * 16 + (lane & 15), k = kk * 32 + (lane >> 4) * 8 + e;
    WdP[i] = (short)bfq(W_d_w[n * 256 + k]);
  }
  for (int i = i0; i < 65536; i += stride) {  // WhhP
    int e = i & 7, lane = (i >> 3) & 63, nt = (i >> 9) & 31, kk = i >> 14;
    int n = nt * 16 + (lane & 15), k = kk * 32 + (lane >> 4) * 8 + e;
    WhhP[i] = (short)bfq(W_hh[n * 128 + k]);
  }
  for (int i = i0; i < 1064960; i += stride) {  // WdecP (blocks 0..64)
    int e = i & 7, lane = (i >> 3) & 63, w = (i >> 9) & 7, kk = (i >> 12) & 3, tt = i >> 14;
    int n = w * 16 + (lane & 15), k = kk * 32 + (lane >> 4) * 8 + e;
    WdecP[i] = (short)bfq(W_dec_w[n * 8320 + tt * 128 + k]);
  }
  for (int i = i0; i < 8192; i += stride) {  // UdP [k2<64][m<128] f16 pairs
    int m = i & 127, k2 = i >> 7;
    UdP[i] = pkh(U_d_w[m * 128 + 2 * k2], U_d_w[m * 128 + 2 * k2 + 1]);
  }
  for (int i = i0; i < 64; i += stride)  // wtP
    wtP[i] = pkh(w_tilda_w[2 * i], w_tilda_w[2 * i + 1]);
  for (int i = i0; i < 16384; i += stride) {  // WyP2
    int jj = i & 63, k = i >> 6;
    WyP2[i] = pkh(W_y_w[(2 * jj) * 256 + k], W_y_w[(2 * jj + 1) * 256 + k]);
  }
}

// ---------------- fused scan ----------------
// LDS (bytes), STATIC:
//   y1u   u32 [p<64][r<8][64]  @ 0       (131072)  E = exp2(CE*y1) f16 pairs
//   cat   u32 [9][132]         @ 131072  (4752)
//   x1c   f32 [8][128]         @ 135824  (4096)    X = exp2(CE*x1)
//   gates f32 [8][516]         @ 139920  (16512)
//   va2   f32 [128]            @ 156432  (512)
//   qpart f32 [16][64]         @ 156944  (4096)
//   wih_s f32 [512]            @ 161040  (2048)
//   ---- epilogue aliases (E dead): beta @ 0 (2048), cat2 @ 4096 (8192)
#define LDS_BYTES 163088

// phase-0 chunk: 8 m-values (2 f32x4 acc, 2 uint4 loads) -> 4 E-pairs in LDS
#define CHUNK8(C)                                                              \
  do {                                                                         \
    f32x4 a0 = {0, 0, 0, 0}, a1 = {0, 0, 0, 0};                                \
    for (int k2 = 0; k2 < 64; ++k2) {                                          \
      float2 ev = ntload2(enc_row + 2 * k2);                                   \
      u32 ep = pkh(ev.x, ev.y);                                                \
      const uint4* uvp = UdP4 + k2 * 32 + h * 16 + (C) * 2;                    \
      uint4 u0 = uvp[0], u1 = uvp[1];                                          \
      a0.x = dot2h(ep, u0.x, a0.x); a0.y = dot2h(ep, u0.y, a0.y);              \
      a0.z = dot2h(ep, u0.z, a0.z); a0.w = dot2h(ep, u0.w, a0.w);              \
      a1.x = dot2h(ep, u1.x, a1.x); a1.y = dot2h(ep, u1.y, a1.y);              \
      a1.z = dot2h(ep, u1.z, a1.z); a1.w = dot2h(ep, u1.w, a1.w);              \
    }                                                                          \
    u32* yb = y1u + (h * 32 + (C) * 4) * 512 + r * 64 + lane;                  \
    yb[0 * 512] = pkh(FEXP(CE * a0.x), FEXP(CE * a0.y));                       \
    yb[1 * 512] = pkh(FEXP(CE * a0.z), FEXP(CE * a0.w));                       \
    yb[2 * 512] = pkh(FEXP(CE * a1.x), FEXP(CE * a1.y));                       \
    yb[3 * 512] = pkh(FEXP(CE * a1.z), FEXP(CE * a1.w));                       \
  } while (0)

// phase-B logit group: q += va2[m] * rcp(1 + E[l,m]*X[m]), 8 m-values
#define QGROUP(G)                                                              \
  {                                                                            \
    const int i8 = h * 8 + (G);                                                \
    u32 Y0 = y1u[(i8 * 4 + 0) * 512 + r * 64 + lane];                          \
    u32 Y1 = y1u[(i8 * 4 + 1) * 512 + r * 64 + lane];                          \
    u32 Y2 = y1u[(i8 * 4 + 2) * 512 + r * 64 + lane];                          \
    u32 Y3 = y1u[(i8 * 4 + 3) * 512 + r * 64 + lane];                          \
    float4 xa = *(const float4*)(x1c + r * 128 + i8 * 8);                      \
    float4 xb = *(const float4*)(x1c + r * 128 + i8 * 8 + 4);                  \
    float4 va = *(const float4*)(va2 + i8 * 8);                                \
    float4 vb = *(const float4*)(va2 + i8 * 8 + 4);                            \
    h2 p;                                                                      \
    p = as_h2(Y0);                                                             \
    q0 = fmaf(va.x, fast_rcp(fmaf((float)p.x, xa.x, 1.f)), q0);                \
    q1 = fmaf(va.y, fast_rcp(fmaf((float)p.y, xa.y, 1.f)), q1);                \
    p = as_h2(Y1);                                                             \
    q2 = fmaf(va.z, fast_rcp(fmaf((float)p.x, xa.z, 1.f)), q2);                \
    q3 = fmaf(va.w, fast_rcp(fmaf((float)p.y, xa.w, 1.f)), q3);                \
    p = as_h2(Y2);                                                             \
    q0 = fmaf(vb.x, fast_rcp(fmaf((float)p.x, xb.x, 1.f)), q0);                \
    q1 = fmaf(vb.y, fast_rcp(fmaf((float)p.y, xb.y, 1.f)), q1);                \
    p = as_h2(Y3);                                                             \
    q2 = fmaf(vb.z, fast_rcp(fmaf((float)p.x, xb.z, 1.f)), q2);                \
    q3 = fmaf(vb.w, fast_rcp(fmaf((float)p.y, xb.w, 1.f)), q3);                \
  }

#define AFRAG(KK) (*(const s16x8*)(cat_u + arow + (KK) * 16))

__global__ __launch_bounds__(NTH)
__attribute__((amdgpu_waves_per_eu(4, 4)))
void fused_main(
    const float* __restrict__ enc, const float* __restrict__ y,
    const float* __restrict__ W_d_b, const float* __restrict__ v_d_w,
    const float* __restrict__ w_tilda_w, const float* __restrict__ w_tilda_b,
    const float* __restrict__ W_ih, const float* __restrict__ b_ih,
    const float* __restrict__ b_hh, const float* __restrict__ W_dec_b,
    const float* __restrict__ W_y_b, const float* __restrict__ v_y_w,
    const float* __restrict__ v_y_b,
    const short* __restrict__ WdP, const short* __restrict__ WhhP,
    const short* __restrict__ WdecP, const uint4* __restrict__ UdP4,
    const u32* __restrict__ wtP, const u32* __restrict__ WyP2,
    float* __restrict__ out) {
  __shared__ char lds[LDS_BYTES];
  u32* y1u = (u32*)lds;
  u32* cat_u = (u32*)(lds + 131072);
  float* x1c = (float*)(lds + 135824);
  float* gates = (float*)(lds + 139920);
  float* va2 = (float*)(lds + 156432);
  float* qpart = (float*)(lds + 156944);
  float* wih_s = (float*)(lds + 161040);
  float* beta_s = (float*)lds;           // written at t=Tn-1 (E reads done)
  float* cat2 = (float*)(lds + 4096);    // epilogue alias (E dead)

  const int tid = threadIdx.x;
  const int lane = tid & 63;
  const int wv = tid >> 6;   // 0..15
  const int r = wv & 7;      // batch sub-row
  const int h = wv >> 3;     // m-half owner
  const int b = blockIdx.x * NB + r;
  const int j = lane;

  for (int i = tid; i < 1188; i += NTH) cat_u[i] = 0u;
  if (wv == 0) {
    va2[lane] = 2.f * v_d_w[lane];
    va2[64 + lane] = 2.f * v_d_w[64 + lane];
  }
  for (int i = tid; i < 512; i += NTH) wih_s[i] = W_ih[i];

  // ---- phase 0: E = exp2(CE*y1) m-half -> LDS; ew (h==0 only) ----
  const float* enc_row = enc + ((size_t)b * 64 + lane) * 128;
  float ew = 0.f;
  if (h == 0) {
    for (int k2 = 0; k2 < 64; ++k2) {
      float2 ev = ntload2(enc_row + 2 * k2);
      ew = dot2h(pkh(ev.x, ev.y), wtP[k2], ew);
    }
  }
  CHUNK8(0); CHUNK8(1); CHUNK8(2); CHUNK8(3);
  CHUNK8(4); CHUNK8(5); CHUNK8(6); CHUNK8(7);

  const float wt_y = w_tilda_w[128];
  const float wt_b0 = w_tilda_b[0];
  float sv = v_d_w[lane] + v_d_w[64 + lane];
#pragma unroll
  for (int off = 32; off; off >>= 1) sv += __shfl_xor(sv, off, 64);

  const int ccol = lane & 15;
  const int crow = (lane >> 4) * 4;
  const int arow = (ccol < 8 ? ccol : 8) * 132 + (lane >> 4) * 4;
  const float wdb_n = W_d_b[r * 16 + ccol];
  const float dfb_n = W_dec_b[r * 16 + ccol];
  const float bini0 = b_ih[wv * 32 + ccol] + b_hh[wv * 32 + ccol];
  const float bini1 = b_ih[wv * 32 + 16 + ccol] + b_hh[wv * 32 + 16 + ccol];
  f32x4 dfacc = {dfb_n, dfb_n, dfb_n, dfb_n};
  float s0 = 0.f, s1 = 0.f;

  __syncthreads();

#pragma unroll 1
  for (int t = 0; t < Tn; ++t) {
    // ---- phase A: GEMMs, loads grouped x4 ahead of MFMAs ----
    if (wv < 8) {
      const s16x8* WdF = (const s16x8*)WdP;
      f32x4 c1 = {wdb_n, wdb_n, wdb_n, wdb_n};
      s16x8 b0 = WdF[(0 * 8 + wv) * 64 + lane];
      s16x8 b1 = WdF[(1 * 8 + wv) * 64 + lane];
      s16x8 b2 = WdF[(2 * 8 + wv) * 64 + lane];
      s16x8 b3 = WdF[(3 * 8 + wv) * 64 + lane];
      c1 = MFMA16(AFRAG(0), b0, c1);
      c1 = MFMA16(AFRAG(1), b1, c1);
      c1 = MFMA16(AFRAG(2), b2, c1);
      c1 = MFMA16(AFRAG(3), b3, c1);
      b0 = WdF[(4 * 8 + wv) * 64 + lane];
      b1 = WdF[(5 * 8 + wv) * 64 + lane];
      b2 = WdF[(6 * 8 + wv) * 64 + lane];
      b3 = WdF[(7 * 8 + wv) * 64 + lane];
      c1 = MFMA16(AFRAG(4), b0, c1);
      c1 = MFMA16(AFRAG(5), b1, c1);
      c1 = MFMA16(AFRAG(6), b2, c1);
      c1 = MFMA16(AFRAG(7), b3, c1);
      if (crow < 8) {
#pragma unroll
        for (int r4 = 0; r4 < 4; ++r4)
          x1c[(crow + r4) * 128 + wv * 16 + ccol] = FEXP(c1[r4] * CE);
      }
    } else {
      const s16x8* WdcF = (const s16x8*)WdecP;
      s16x8 b0 = WdcF[((t * 4 + 0) * 8 + r) * 64 + lane];
      s16x8 b1 = WdcF[((t * 4 + 1) * 8 + r) * 64 + lane];
      s16x8 b2 = WdcF[((t * 4 + 2) * 8 + r) * 64 + lane];
      s16x8 b3 = WdcF[((t * 4 + 3) * 8 + r) * 64 + lane];
      dfacc = MFMA16(AFRAG(0), b0, dfacc);
      dfacc = MFMA16(AFRAG(1), b1, dfacc);
      dfacc = MFMA16(AFRAG(2), b2, dfacc);
      dfacc = MFMA16(AFRAG(3), b3, dfacc);
    }
    {
      const s16x8* WhF = (const s16x8*)WhhP;
      const int nt0 = wv * 2;
      s16x8 b0 = WhF[(0 * 32 + nt0) * 64 + lane];
      s16x8 b1 = WhF[(1 * 32 + nt0) * 64 + lane];
      s16x8 b2 = WhF[(2 * 32 + nt0) * 64 + lane];
      s16x8 b3 = WhF[(3 * 32 + nt0) * 64 + lane];
      f32x4 c2 = {bini0, bini0, bini0, bini0};
      c2 = MFMA16(AFRAG(0), b0, c2);
      c2 = MFMA16(AFRAG(1), b1, c2);
      c2 = MFMA16(AFRAG(2), b2, c2);
      c2 = MFMA16(AFRAG(3), b3, c2);
      b0 = WhF[(0 * 32 + nt0 + 1) * 64 + lane];
      b1 = WhF[(1 * 32 + nt0 + 1) * 64 + lane];
      b2 = WhF[(2 * 32 + nt0 + 1) * 64 + lane];
      b3 = WhF[(3 * 32 + nt0 + 1) * 64 + lane];
      f32x4 c3 = {bini1, bini1, bini1, bini1};
      c3 = MFMA16(AFRAG(0), b0, c3);
      c3 = MFMA16(AFRAG(1), b1, c3);
      c3 = MFMA16(AFRAG(2), b2, c3);
      c3 = MFMA16(AFRAG(3), b3, c3);
      if (crow < 8) {
#pragma unroll
        for (int r4 = 0; r4 < 4; ++r4) {
          gates[(crow + r4) * 516 + nt0 * 16 + ccol] = c2[r4];
          gates[(crow + r4) * 516 + (nt0 + 1) * 16 + ccol] = c3[r4];
        }
      }
    }
    __syncthreads();

    // ---- phase B: partial logits over this wave's m-half ----
    float q0 = 0.f, q1 = 0.f, q2 = 0.f, q3 = 0.f;
    QGROUP(0) QGROUP(1) QGROUP(2) QGROUP(3)
    QGROUP(4) QGROUP(5) QGROUP(6) QGROUP(7)
    qpart[wv * 64 + lane] = q0 + q1 + q2 + q3;
    __syncthreads();

    if (h == 0) {
      float lg = sv - (qpart[r * 64 + lane] + qpart[(r + 8) * 64 + lane]);
      float pexp = __expf(lg);  // |lg| bounded ~15: no max pass needed
      float smv = pexp, yt = pexp * ew;
#pragma unroll
      for (int off = 32; off; off >>= 1) {
        smv += __shfl_xor(smv, off, 64);
        yt += __shfl_xor(yt, off, 64);
      }
      float rs = fast_rcp(smv);
      if (t == Tn - 1) beta_s[r * 64 + lane] = pexp * rs;  // E reads done
      float ytil = yt * rs + y[(size_t)b * 64 + t] * wt_y + wt_b0;

      float2 gi = *(const float2*)(gates + r * 516 + 2 * j);
      float2 gf = *(const float2*)(gates + r * 516 + 128 + 2 * j);
      float2 gg = *(const float2*)(gates + r * 516 + 256 + 2 * j);
      float2 go = *(const float2*)(gates + r * 516 + 384 + 2 * j);
      float2 wi0 = *(const float2*)(wih_s + 2 * j);
      float2 wi1 = *(const float2*)(wih_s + 128 + 2 * j);
      float2 wi2 = *(const float2*)(wih_s + 256 + 2 * j);
      float2 wi3 = *(const float2*)(wih_s + 384 + 2 * j);
      float i0 = fast_sig(gi.x + ytil * wi0.x);
      float i1 = fast_sig(gi.y + ytil * wi0.y);
      float f0 = fast_sig(gf.x + ytil * wi1.x);
      float f1 = fast_sig(gf.y + ytil * wi1.y);
      float g0 = fast_tanh(gg.x + ytil * wi2.x);
      float g1 = fast_tanh(gg.y + ytil * wi2.y);
      float o0 = fast_sig(go.x + ytil * wi3.x);
      float o1 = fast_sig(go.y + ytil * wi3.y);
      s0 = f0 * s0 + i0 * g0;
      s1 = f1 * s1 + i1 * g1;
      float d0 = o0 * fast_tanh(s0);
      float d1 = o1 * fast_tanh(s1);
      cat_u[r * 132 + j] = pack2bf(d0, d1);
      cat_u[r * 132 + 64 + j] = pack2bf(s0, s1);
    }
    __syncthreads();
  }

  // ---- epilogue (E region dead; beta already written; cat2 aliases E) ----
  if (wv >= 8) {  // finish d_fin with Wdec block 64, write cat2 cols 0-127
    const s16x8* WdcF = (const s16x8*)WdecP;
    s16x8 b0 = WdcF[((64 * 4 + 0) * 8 + r) * 64 + lane];
    s16x8 b1 = WdcF[((64 * 4 + 1) * 8 + r) * 64 + lane];
    s16x8 b2 = WdcF[((64 * 4 + 2) * 8 + r) * 64 + lane];
    s16x8 b3 = WdcF[((64 * 4 + 3) * 8 + r) * 64 + lane];
    dfacc = MFMA16(AFRAG(0), b0, dfacc);
    dfacc = MFMA16(AFRAG(1), b1, dfacc);
    dfacc = MFMA16(AFRAG(2), b2, dfacc);
    dfacc = MFMA16(AFRAG(3), b3, dfacc);
    if (crow < 8) {
#pragma unroll
      for (int r4 = 0; r4 < 4; ++r4)
        cat2[(crow + r4) * 256 + r * 16 + ccol] = dfacc[r4];
    }
  }
  __syncthreads();

  if (h == 0) {
    // c_T
    float c0 = 0.f, c1v = 0.f;
#pragma unroll 2
    for (int it = 0; it < 16; ++it) {
      float4 bv = *(const float4*)(beta_s + r * 64 + it * 4);
      float2 e0 = ntload2(enc + ((size_t)b * 64 + it * 4 + 0) * 128 + 2 * j);
      float2 e1 = ntload2(enc + ((size_t)b * 64 + it * 4 + 1) * 128 + 2 * j);
      float2 e2 = ntload2(enc + ((size_t)b * 64 + it * 4 + 2) * 128 + 2 * j);
      float2 e3 = ntload2(enc + ((size_t)b * 64 + it * 4 + 3) * 128 + 2 * j);
      c0 = fmaf(bv.x, e0.x, c0); c1v = fmaf(bv.x, e0.y, c1v);
      c0 = fmaf(bv.y, e1.x, c0); c1v = fmaf(bv.y, e1.y, c1v);
      c0 = fmaf(bv.z, e2.x, c0); c1v = fmaf(bv.z, e2.y, c1v);
      c0 = fmaf(bv.w, e3.x, c0); c1v = fmaf(bv.w, e3.y, c1v);
    }
    *(float2*)(cat2 + r * 256 + 128 + 2 * j) = make_float2(c0, c1v);

    // final head
    float2 hb = *(const float2*)(W_y_b + 2 * j);
    float h0v = hb.x, h1v = hb.y;
#pragma unroll 4
    for (int it = 0; it < 64; ++it) {
      float4 cv = *(const float4*)(cat2 + r * 256 + it * 4);
      u32 w0 = WyP2[(it * 4 + 0) * 64 + j];
      u32 w1 = WyP2[(it * 4 + 1) * 64 + j];
      u32 w2 = WyP2[(it * 4 + 2) * 64 + j];
      u32 w3 = WyP2[(it * 4 + 3) * 64 + j];
      h2 p0 = as_h2(w0), p1 = as_h2(w1), p2 = as_h2(w2), p3 = as_h2(w3);
      h0v = fmaf(cv.x, (float)p0.x, h0v); h1v = fmaf(cv.x, (float)p0.y, h1v);
      h0v = fmaf(cv.y, (float)p1.x, h0v); h1v = fmaf(cv.y, (float)p1.y, h1v);
      h0v = fmaf(cv.z, (float)p2.x, h0v); h1v = fmaf(cv.z, (float)p2.y, h1v);
      h0v = fmaf(cv.w, (float)p3.x, h0v); h1v = fmaf(cv.w, (float)p3.y, h1v);
    }
    float2 vy = *(const float2*)(v_y_w + 2 * j);
    float rsum = h0v * vy.x + h1v * vy.y;
#pragma unroll
    for (int off = 32; off; off >>= 1) rsum += __shfl_xor(rsum, off, 64);
    if (lane == 0) out[b] = rsum + v_y_b[0];
  }
}

extern "C" void kernel_launch(void* const* d_in, const int* in_sizes, int n_in,
                              void* d_out, int out_size, void* d_ws, size_t ws_size,
                              hipStream_t stream) {
  const float* enc = (const float*)d_in[0];
  const float* y = (const float*)d_in[1];
  const float* W_d_w = (const float*)d_in[2];
  const float* W_d_b = (const float*)d_in[3];
  const float* U_d_w = (const float*)d_in[4];
  const float* v_d_w = (const float*)d_in[5];
  const float* w_tilda_w = (const float*)d_in[6];
  const float* w_tilda_b = (const float*)d_in[7];
  const float* W_ih = (const float*)d_in[8];
  const float* b_ih = (const float*)d_in[9];
  const float* W_hh = (const float*)d_in[10];
  const float* b_hh = (const float*)d_in[11];
  const float* W_dec_w = (const float*)d_in[12];
  const float* W_dec_b = (const float*)d_in[13];
  const float* W_y_w = (const float*)d_in[14];
  const float* W_y_b = (const float*)d_in[15];
  const float* v_y_w = (const float*)d_in[16];
  const float* v_y_b = (const float*)d_in[17];

  char* ws = (char*)d_ws;
  short* WdP = (short*)(ws + 0);
  short* WhhP = (short*)(ws + 65536);
  short* WdecP = (short*)(ws + 196608);
  u32* UdP = (u32*)(ws + 2326528);
  u32* wtP = (u32*)(ws + 2359296);
  u32* WyP2 = (u32*)(ws + 2359552);

  pack_weights<<<512, 256, 0, stream>>>(W_d_w, W_hh, W_dec_w, W_y_w, U_d_w,
                                        w_tilda_w, WdP, WhhP, WdecP, UdP, wtP, WyP2);
  fused_main<<<4096 / NB, NTH, 0, stream>>>(
      enc, y, W_d_b, v_d_w, w_tilda_w, w_tilda_b, W_ih, b_ih, b_hh, W_dec_b,
      W_y_b, v_y_w, v_y_b, WdP, WhhP, WdecP, (const uint4*)UdP, wtP, WyP2,
      (float*)d_out);
}

// Round 13
// 1854.978 us; speedup vs baseline: 1.3951x; 1.3951x over previous
//
#include <hip/hip_runtime.h>
#include <hip/hip_bf16.h>

#define Tn 64
#define NB 16
#define NTH 1024

typedef unsigned int u32;
typedef _Float16 h2 __attribute__((ext_vector_type(2)));
typedef __fp16 fp16x2 __attribute__((ext_vector_type(2)));
typedef short s16x8 __attribute__((ext_vector_type(8)));
typedef float f32x4 __attribute__((ext_vector_type(4)));

#define MFMA16(a, b, c) __builtin_amdgcn_mfma_f32_16x16x32_bf16(a, b, c, 0, 0, 0)

__device__ __forceinline__ h2 as_h2(u32 u) { union { u32 u; h2 h; } c; c.u = u; return c.h; }

__device__ __forceinline__ float dot2h(u32 a, u32 w, float acc) {
  return __builtin_amdgcn_fdot2(as_h2(a), as_h2(w), acc, false);
}

__device__ __forceinline__ u32 pkh(float a, float b) {
  union { u32 u; fp16x2 h; } c;
  c.h = __builtin_amdgcn_cvt_pkrtz(a, b);
  return c.u;
}

__device__ __forceinline__ unsigned short bfq(float x) {
  u32 u = __float_as_uint(x);
  return (unsigned short)((u + 0x7fffu + ((u >> 16) & 1)) >> 16);
}

__device__ __forceinline__ u32 pack2bf(float a, float b) {
  u32 ua = __float_as_uint(a), ub = __float_as_uint(b);
  ua = (ua + 0x7fffu + ((ua >> 16) & 1)) >> 16;
  ub = (ub + 0x7fffu + ((ub >> 16) & 1)) >> 16;
  return (ua & 0xffffu) | (ub << 16);
}

#define FEXP(x) __builtin_amdgcn_exp2f(x)
#define CE 2.885390081777927f /* 2*log2(e) */

__device__ __forceinline__ float fast_rcp(float x) { return __builtin_amdgcn_rcpf(x); }
__device__ __forceinline__ float fast_tanh(float x) {
  float e = __expf(2.f * x);
  return 1.f - 2.f * fast_rcp(1.f + e);
}
__device__ __forceinline__ float fast_sig(float x) {
  return fast_rcp(1.f + __expf(-x));
}

// ---------------- weight pre-pack (unchanged layouts) ----------------
__global__ void pack_weights(const float* __restrict__ W_d_w,
                             const float* __restrict__ W_hh,
                             const float* __restrict__ W_dec_w,
                             const float* __restrict__ W_y_w,
                             const float* __restrict__ U_d_w,
                             const float* __restrict__ w_tilda_w,
                             short* __restrict__ WdP, short* __restrict__ WhhP,
                             short* __restrict__ WdecP, u32* __restrict__ UdP,
                             u32* __restrict__ wtP, u32* __restrict__ WyP2) {
  const int i0 = blockIdx.x * blockDim.x + threadIdx.x;
  const int stride = gridDim.x * blockDim.x;
  for (int i = i0; i < 32768; i += stride) {  // WdP
    int e = i & 7, lane = (i >> 3) & 63, w = (i >> 9) & 7, kk = i >> 12;
    int n = w * 16 + (lane & 15), k = kk * 32 + (lane >> 4) * 8 + e;
    WdP[i] = (short)bfq(W_d_w[n * 256 + k]);
  }
  for (int i = i0; i < 65536; i += stride) {  // WhhP
    int e = i & 7, lane = (i >> 3) & 63, nt = (i >> 9) & 31, kk = i >> 14;
    int n = nt * 16 + (lane & 15), k = kk * 32 + (lane >> 4) * 8 + e;
    WhhP[i] = (short)bfq(W_hh[n * 128 + k]);
  }
  for (int i = i0; i < 1064960; i += stride) {  // WdecP (blocks 0..64)
    int e = i & 7, lane = (i >> 3) & 63, w = (i >> 9) & 7, kk = (i >> 12) & 3, tt = i >> 14;
    int n = w * 16 + (lane & 15), k = kk * 32 + (lane >> 4) * 8 + e;
    WdecP[i] = (short)bfq(W_dec_w[n * 8320 + tt * 128 + k]);
  }
  for (int i = i0; i < 8192; i += stride) {  // UdP [k2<64][m<128] f16 pairs
    int m = i & 127, k2 = i >> 7;
    UdP[i] = pkh(U_d_w[m * 128 + 2 * k2], U_d_w[m * 128 + 2 * k2 + 1]);
  }
  for (int i = i0; i < 64; i += stride)  // wtP
    wtP[i] = pkh(w_tilda_w[2 * i], w_tilda_w[2 * i + 1]);
  for (int i = i0; i < 16384; i += stride) {  // WyP2
    int jj = i & 63, k = i >> 6;
    WyP2[i] = pkh(W_y_w[(2 * jj) * 256 + k], W_y_w[(2 * jj + 1) * 256 + k]);
  }
}

// ---------------- fused scan ----------------
// LDS (bytes), STATIC:
//   E     u32 [p<32][r<16][l<64]  @ 0       (131072)  E=exp2(CE*y1) pairs 0-31
//   cat   u32 [16][132]           @ 131072  (8448)
//   x1h   f16 [16][128]           @ 139520  (4096)    X = exp2(CE*x1)
//   gth   f16 [16][512]           @ 143616  (16384)   gates
//   va2   f32 [128]               @ 160000  (512)
//   wih_s f32 [512]               @ 160512  (2048)
//   ---- epilogue aliases (E dead): beta @ 0 (4096), cat2 @ 4096 (16384)
#define LDS_BYTES 162560

#define CHUNK_CORE(C)                                                          \
    f32x4 a0 = {0, 0, 0, 0}, a1 = {0, 0, 0, 0};                                \
    for (int k2 = 0; k2 < 64; ++k2) {                                          \
      float2 ev = *(const float2*)(enc_row + 2 * k2);                          \
      u32 ep = pkh(ev.x, ev.y);                                                \
      const uint4* uvp = UdP4 + k2 * 32 + (C) * 2;                             \
      uint4 u0 = uvp[0], u1 = uvp[1];                                          \
      a0.x = dot2h(ep, u0.x, a0.x); a0.y = dot2h(ep, u0.y, a0.y);              \
      a0.z = dot2h(ep, u0.z, a0.z); a0.w = dot2h(ep, u0.w, a0.w);              \
      a1.x = dot2h(ep, u1.x, a1.x); a1.y = dot2h(ep, u1.y, a1.y);              \
      a1.z = dot2h(ep, u1.z, a1.z); a1.w = dot2h(ep, u1.w, a1.w);              \
    }

#define CHUNK_LDS(C)                                                           \
  do {                                                                         \
    CHUNK_CORE(C)                                                              \
    u32* yb = E + ((C) * 4) * 1024 + wv * 64 + lane;                           \
    yb[0]    = pkh(FEXP(CE * a0.x), FEXP(CE * a0.y));                          \
    yb[1024] = pkh(FEXP(CE * a0.z), FEXP(CE * a0.w));                          \
    yb[2048] = pkh(FEXP(CE * a1.x), FEXP(CE * a1.y));                          \
    yb[3072] = pkh(FEXP(CE * a1.z), FEXP(CE * a1.w));                          \
  } while (0)

#define CHUNK_REG(C, OUT)                                                      \
  do {                                                                         \
    CHUNK_CORE(C)                                                              \
    OUT = make_uint4(pkh(FEXP(CE * a0.x), FEXP(CE * a0.y)),                    \
                     pkh(FEXP(CE * a0.z), FEXP(CE * a0.w)),                    \
                     pkh(FEXP(CE * a1.x), FEXP(CE * a1.y)),                    \
                     pkh(FEXP(CE * a1.z), FEXP(CE * a1.w)));                   \
  } while (0)

// logit group core: 4 E-pairs, 4 X-pairs (f16), 8 va values
#define QCORE(Y0, Y1, Y2, Y3, G)                                               \
  {                                                                            \
    const u32* xp = (const u32*)(x1h + wv * 128 + (G) * 8);                    \
    u32 X0 = xp[0], X1 = xp[1], X2 = xp[2], X3 = xp[3];                        \
    float4 va = *(const float4*)(va2 + (G) * 8);                               \
    float4 vb = *(const float4*)(va2 + (G) * 8 + 4);                           \
    h2 e, x;                                                                   \
    e = as_h2(Y0); x = as_h2(X0);                                              \
    q0 = fmaf(va.x, fast_rcp(fmaf((float)e.x, (float)x.x, 1.f)), q0);          \
    q1 = fmaf(va.y, fast_rcp(fmaf((float)e.y, (float)x.y, 1.f)), q1);          \
    e = as_h2(Y1); x = as_h2(X1);                                              \
    q2 = fmaf(va.z, fast_rcp(fmaf((float)e.x, (float)x.x, 1.f)), q2);          \
    q3 = fmaf(va.w, fast_rcp(fmaf((float)e.y, (float)x.y, 1.f)), q3);          \
    e = as_h2(Y2); x = as_h2(X2);                                              \
    q0 = fmaf(vb.x, fast_rcp(fmaf((float)e.x, (float)x.x, 1.f)), q0);          \
    q1 = fmaf(vb.y, fast_rcp(fmaf((float)e.y, (float)x.y, 1.f)), q1);          \
    e = as_h2(Y3); x = as_h2(X3);                                              \
    q2 = fmaf(vb.z, fast_rcp(fmaf((float)e.x, (float)x.x, 1.f)), q2);          \
    q3 = fmaf(vb.w, fast_rcp(fmaf((float)e.y, (float)x.y, 1.f)), q3);          \
  }

#define QGROUP_L(G)                                                            \
  {                                                                            \
    const u32* Eb = E + (G) * 4 * 1024 + wv * 64 + lane;                       \
    QCORE(Eb[0], Eb[1024], Eb[2048], Eb[3072], G)                              \
  }
#define QGROUP_R(G, Y) QCORE((Y).x, (Y).y, (Y).z, (Y).w, G)

#define AFRAG(KK) (*(const s16x8*)(cat_u + arow + (KK) * 16))

__global__ __launch_bounds__(NTH)
__attribute__((amdgpu_waves_per_eu(4, 4)))
void fused_main(
    const float* __restrict__ enc, const float* __restrict__ y,
    const float* __restrict__ W_d_b, const float* __restrict__ v_d_w,
    const float* __restrict__ w_tilda_w, const float* __restrict__ w_tilda_b,
    const float* __restrict__ W_ih, const float* __restrict__ b_ih,
    const float* __restrict__ b_hh, const float* __restrict__ W_dec_b,
    const float* __restrict__ W_y_b, const float* __restrict__ v_y_w,
    const float* __restrict__ v_y_b,
    const short* __restrict__ WdP, const short* __restrict__ WhhP,
    const short* __restrict__ WdecP, const uint4* __restrict__ UdP4,
    const u32* __restrict__ wtP, const u32* __restrict__ WyP2,
    float* __restrict__ out) {
  __shared__ char lds[LDS_BYTES];
  u32* E = (u32*)lds;
  u32* cat_u = (u32*)(lds + 131072);
  _Float16* x1h = (_Float16*)(lds + 139520);
  _Float16* gth = (_Float16*)(lds + 143616);
  float* va2 = (float*)(lds + 160000);
  float* wih_s = (float*)(lds + 160512);
  float* beta_s = (float*)lds;           // epilogue alias (E dead)
  float* cat2 = (float*)(lds + 4096);    // epilogue alias (E dead)

  const int tid = threadIdx.x;
  const int lane = tid & 63;
  const int wv = tid >> 6;   // 0..15 == batch row
  const int b = blockIdx.x * NB + wv;
  const int j = lane;

  for (int i = tid; i < 16 * 132; i += NTH) cat_u[i] = 0u;
  if (wv == 0) {
    va2[lane] = 2.f * v_d_w[lane];
    va2[64 + lane] = 2.f * v_d_w[64 + lane];
  }
  for (int i = tid; i < 512; i += NTH) wih_s[i] = W_ih[i];

  // ---- phase 0: E for own row -> 32 pairs LDS + 32 pairs regs; ew ----
  const float* enc_row = enc + ((size_t)b * 64 + lane) * 128;
  float ew = 0.f;
  for (int k2 = 0; k2 < 64; ++k2) {
    float2 ev = *(const float2*)(enc_row + 2 * k2);
    ew = dot2h(pkh(ev.x, ev.y), wtP[k2], ew);
  }
  CHUNK_LDS(0); CHUNK_LDS(1); CHUNK_LDS(2); CHUNK_LDS(3);
  CHUNK_LDS(4); CHUNK_LDS(5); CHUNK_LDS(6); CHUNK_LDS(7);
  uint4 Yr0, Yr1, Yr2, Yr3, Yr4, Yr5, Yr6, Yr7;
  CHUNK_REG(8, Yr0);  CHUNK_REG(9, Yr1);  CHUNK_REG(10, Yr2); CHUNK_REG(11, Yr3);
  CHUNK_REG(12, Yr4); CHUNK_REG(13, Yr5); CHUNK_REG(14, Yr6); CHUNK_REG(15, Yr7);

  const float wt_y = w_tilda_w[128];
  const float wt_b0 = w_tilda_b[0];
  float svv = v_d_w[lane] + v_d_w[64 + lane];
#pragma unroll
  for (int off = 32; off; off >>= 1) svv += __shfl_xor(svv, off, 64);
  const float sv = __int_as_float(__builtin_amdgcn_readfirstlane(__float_as_int(svv)));

  const int ccol = lane & 15;
  const int crow = (lane >> 4) * 4;
  const int arow = ccol * 132 + (lane >> 4) * 4;
  const float wdb_n = W_d_b[(wv & 7) * 16 + ccol];
  const float dfb_n = W_dec_b[(wv & 7) * 16 + ccol];
  const float bini0 = b_ih[wv * 32 + ccol] + b_hh[wv * 32 + ccol];
  const float bini1 = b_ih[wv * 32 + 16 + ccol] + b_hh[wv * 32 + 16 + ccol];
  f32x4 dfacc = {dfb_n, dfb_n, dfb_n, dfb_n};
  float s0 = 0.f, s1 = 0.f, beta_sv = 0.f;

  __syncthreads();

#pragma unroll 1
  for (int t = 0; t < Tn; ++t) {
    // ---- phase A: GEMMs on matrix pipe ----
    if (wv < 8) {
      f32x4 c1 = {wdb_n, wdb_n, wdb_n, wdb_n};
#pragma unroll
      for (int kk = 0; kk < 8; ++kk) {
        s16x8 bf = *(const s16x8*)(WdP + (((kk * 8 + wv) * 64 + lane) * 8));
        c1 = MFMA16(AFRAG(kk), bf, c1);
      }
#pragma unroll
      for (int r4 = 0; r4 < 4; ++r4)
        x1h[(crow + r4) * 128 + wv * 16 + ccol] = (_Float16)FEXP(c1[r4] * CE);
    } else {
      const int w8 = wv - 8;
#pragma unroll
      for (int kk = 0; kk < 4; ++kk) {
        s16x8 bf = *(const s16x8*)(WdecP + ((((t * 4 + kk) * 8 + w8) * 64 + lane) * 8));
        dfacc = MFMA16(AFRAG(kk), bf, dfacc);
      }
    }
#pragma unroll
    for (int it = 0; it < 2; ++it) {
      const float bini = it ? bini1 : bini0;
      f32x4 c2 = {bini, bini, bini, bini};
      const int nt = wv * 2 + it;
#pragma unroll
      for (int kk = 0; kk < 4; ++kk) {
        s16x8 bf = *(const s16x8*)(WhhP + (((kk * 32 + nt) * 64 + lane) * 8));
        c2 = MFMA16(AFRAG(kk), bf, c2);
      }
#pragma unroll
      for (int r4 = 0; r4 < 4; ++r4)
        gth[(crow + r4) * 512 + nt * 16 + ccol] = (_Float16)c2[r4];
    }
    __syncthreads();

    // ---- phase B: full logits for own row ----
    float q0 = 0.f, q1 = 0.f, q2 = 0.f, q3 = 0.f;
    QGROUP_L(0) QGROUP_L(1) QGROUP_L(2) QGROUP_L(3)
    QGROUP_L(4) QGROUP_L(5) QGROUP_L(6) QGROUP_L(7)
    QGROUP_R(8, Yr0)  QGROUP_R(9, Yr1)  QGROUP_R(10, Yr2) QGROUP_R(11, Yr3)
    QGROUP_R(12, Yr4) QGROUP_R(13, Yr5) QGROUP_R(14, Yr6) QGROUP_R(15, Yr7)
    float lg = sv - (q0 + q1 + q2 + q3);
    float pexp = __expf(lg);  // |lg| bounded ~15: no max pass needed
    float smv = pexp, yt = pexp * ew;
#pragma unroll
    for (int off = 32; off; off >>= 1) {
      smv += __shfl_xor(smv, off, 64);
      yt += __shfl_xor(yt, off, 64);
    }
    float rs = fast_rcp(smv);
    if (t == Tn - 1) beta_sv = pexp * rs;
    float ytil = yt * rs + y[(size_t)b * 64 + t] * wt_y + wt_b0;

    const u32* gp = (const u32*)(gth + wv * 512 + 2 * j);
    h2 pgi = as_h2(gp[0]);
    h2 pgf = as_h2(gp[64]);
    h2 pgg = as_h2(gp[128]);
    h2 pgo = as_h2(gp[192]);
    float2 wi0 = *(const float2*)(wih_s + 2 * j);
    float2 wi1 = *(const float2*)(wih_s + 128 + 2 * j);
    float2 wi2 = *(const float2*)(wih_s + 256 + 2 * j);
    float2 wi3 = *(const float2*)(wih_s + 384 + 2 * j);
    float i0 = fast_sig((float)pgi.x + ytil * wi0.x);
    float i1 = fast_sig((float)pgi.y + ytil * wi0.y);
    float f0 = fast_sig((float)pgf.x + ytil * wi1.x);
    float f1 = fast_sig((float)pgf.y + ytil * wi1.y);
    float g0 = fast_tanh((float)pgg.x + ytil * wi2.x);
    float g1 = fast_tanh((float)pgg.y + ytil * wi2.y);
    float o0 = fast_sig((float)pgo.x + ytil * wi3.x);
    float o1 = fast_sig((float)pgo.y + ytil * wi3.y);
    s0 = f0 * s0 + i0 * g0;
    s1 = f1 * s1 + i1 * g1;
    float d0 = o0 * fast_tanh(s0);
    float d1 = o1 * fast_tanh(s1);
    cat_u[wv * 132 + j] = pack2bf(d0, d1);
    cat_u[wv * 132 + 64 + j] = pack2bf(s0, s1);
    __syncthreads();
  }

  // ---- epilogue (E dead; beta/cat2 alias it) ----
  beta_s[wv * 64 + lane] = beta_sv;
  if (wv >= 8) {  // finish d_fin with Wdec block 64
    const int w8 = wv - 8;
#pragma unroll
    for (int kk = 0; kk < 4; ++kk) {
      s16x8 bf = *(const s16x8*)(WdecP + ((((64 * 4 + kk) * 8 + w8) * 64 + lane) * 8));
      dfacc = MFMA16(AFRAG(kk), bf, dfacc);
    }
#pragma unroll
    for (int r4 = 0; r4 < 4; ++r4)
      cat2[(crow + r4) * 256 + w8 * 16 + ccol] = dfacc[r4];
  }
  __syncthreads();

  // c_T for own row
  float c0 = 0.f, c1v = 0.f;
#pragma unroll 2
  for (int it = 0; it < 16; ++it) {
    float4 bv = *(const float4*)(beta_s + wv * 64 + it * 4);
    float2 e0 = *(const float2*)(enc + ((size_t)b * 64 + it * 4 + 0) * 128 + 2 * j);
    float2 e1 = *(const float2*)(enc + ((size_t)b * 64 + it * 4 + 1) * 128 + 2 * j);
    float2 e2 = *(const float2*)(enc + ((size_t)b * 64 + it * 4 + 2) * 128 + 2 * j);
    float2 e3 = *(const float2*)(enc + ((size_t)b * 64 + it * 4 + 3) * 128 + 2 * j);
    c0 = fmaf(bv.x, e0.x, c0); c1v = fmaf(bv.x, e0.y, c1v);
    c0 = fmaf(bv.y, e1.x, c0); c1v = fmaf(bv.y, e1.y, c1v);
    c0 = fmaf(bv.z, e2.x, c0); c1v = fmaf(bv.z, e2.y, c1v);
    c0 = fmaf(bv.w, e3.x, c0); c1v = fmaf(bv.w, e3.y, c1v);
  }
  *(float2*)(cat2 + wv * 256 + 128 + 2 * j) = make_float2(c0, c1v);

  // final head for own row
  float2 hb = *(const float2*)(W_y_b + 2 * j);
  float h0v = hb.x, h1v = hb.y;
#pragma unroll 4
  for (int it = 0; it < 64; ++it) {
    float4 cv = *(const float4*)(cat2 + wv * 256 + it * 4);
    u32 w0 = WyP2[(it * 4 + 0) * 64 + j];
    u32 w1 = WyP2[(it * 4 + 1) * 64 + j];
    u32 w2 = WyP2[(it * 4 + 2) * 64 + j];
    u32 w3 = WyP2[(it * 4 + 3) * 64 + j];
    h2 p0 = as_h2(w0), p1 = as_h2(w1), p2 = as_h2(w2), p3 = as_h2(w3);
    h0v = fmaf(cv.x, (float)p0.x, h0v); h1v = fmaf(cv.x, (float)p0.y, h1v);
    h0v = fmaf(cv.y, (float)p1.x, h0v); h1v = fmaf(cv.y, (float)p1.y, h1v);
    h0v = fmaf(cv.z, (float)p2.x, h0v); h1v = fmaf(cv.z, (float)p2.y, h1v);
    h0v = fmaf(cv.w, (float)p3.x, h0v); h1v = fmaf(cv.w, (float)p3.y, h1v);
  }
  float2 vy = *(const float2*)(v_y_w + 2 * j);
  float rsum = h0v * vy.x + h1v * vy.y;
#pragma unroll
  for (int off = 32; off; off >>= 1) rsum += __shfl_xor(rsum, off, 64);
  if (lane == 0) out[b] = rsum + v_y_b[0];
}

extern "C" void kernel_launch(void* const* d_in, const int* in_sizes, int n_in,
                              void* d_out, int out_size, void* d_ws, size_t ws_size,
                              hipStream_t stream) {
  const float* enc = (const float*)d_in[0];
  const float* y = (const float*)d_in[1];
  const float* W_d_w = (const float*)d_in[2];
  const float* W_d_b = (const float*)d_in[3];
  const float* U_d_w = (const float*)d_in[4];
  const float* v_d_w = (const float*)d_in[5];
  const float* w_tilda_w = (const float*)d_in[6];
  const float* w_tilda_b = (const float*)d_in[7];
  const float* W_ih = (const float*)d_in[8];
  const float* b_ih = (const float*)d_in[9];
  const float* W_hh = (const float*)d_in[10];
  const float* b_hh = (const float*)d_in[11];
  const float* W_dec_w = (const float*)d_in[12];
  const float* W_dec_b = (const float*)d_in[13];
  const float* W_y_w = (const float*)d_in[14];
  const float* W_y_b = (const float*)d_in[15];
  const float* v_y_w = (const float*)d_in[16];
  const float* v_y_b = (const float*)d_in[17];

  char* ws = (char*)d_ws;
  short* WdP = (short*)(ws + 0);
  short* WhhP = (short*)(ws + 65536);
  short* WdecP = (short*)(ws + 196608);
  u32* UdP = (u32*)(ws + 2326528);
  u32* wtP = (u32*)(ws + 2359296);
  u32* WyP2 = (u32*)(ws + 2359552);

  pack_weights<<<512, 256, 0, stream>>>(W_d_w, W_hh, W_dec_w, W_y_w, U_d_w,
                                        w_tilda_w, WdP, WhhP, WdecP, UdP, wtP, WyP2);
  fused_main<<<4096 / NB, NTH, 0, stream>>>(
      enc, y, W_d_b, v_d_w, w_tilda_w, w_tilda_b, W_ih, b_ih, b_hh, W_dec_b,
      W_y_b, v_y_w, v_y_b, WdP, WhhP, WdecP, (const uint4*)UdP, wtP, WyP2,
      (float*)d_out);
}

// Round 14
// 1277.013 us; speedup vs baseline: 2.0265x; 1.4526x over previous
//
#include <hip/hip_runtime.h>
#include <hip/hip_bf16.h>

#define Tn 64
#define NB 16
#define NTH 1024

typedef unsigned int u32;
typedef _Float16 h2 __attribute__((ext_vector_type(2)));
typedef __fp16 fp16x2 __attribute__((ext_vector_type(2)));
typedef short s16x8 __attribute__((ext_vector_type(8)));
typedef float f32x4 __attribute__((ext_vector_type(4)));

#define MFMA16(a, b, c) __builtin_amdgcn_mfma_f32_16x16x32_bf16(a, b, c, 0, 0, 0)

__device__ __forceinline__ h2 as_h2(u32 u) { union { u32 u; h2 h; } c; c.u = u; return c.h; }

__device__ __forceinline__ float dot2h(u32 a, u32 w, float acc) {
  return __builtin_amdgcn_fdot2(as_h2(a), as_h2(w), acc, false);
}

__device__ __forceinline__ u32 pkh(float a, float b) {
  union { u32 u; fp16x2 h; } c;
  c.h = __builtin_amdgcn_cvt_pkrtz(a, b);
  return c.u;
}

__device__ __forceinline__ unsigned short bfq(float x) {
  u32 u = __float_as_uint(x);
  return (unsigned short)((u + 0x7fffu + ((u >> 16) & 1)) >> 16);
}

__device__ __forceinline__ u32 pack2bf(float a, float b) {
  u32 ua = __float_as_uint(a), ub = __float_as_uint(b);
  ua = (ua + 0x7fffu + ((ua >> 16) & 1)) >> 16;
  ub = (ub + 0x7fffu + ((ub >> 16) & 1)) >> 16;
  return (ua & 0xffffu) | (ub << 16);
}

#define FEXP(x) __builtin_amdgcn_exp2f(x)
#define CE 2.885390081777927f /* 2*log2(e) */

__device__ __forceinline__ float fast_rcp(float x) { return __builtin_amdgcn_rcpf(x); }
__device__ __forceinline__ float fast_tanh(float x) {
  float e = __expf(2.f * x);
  return 1.f - 2.f * fast_rcp(1.f + e);
}
__device__ __forceinline__ float fast_sig(float x) {
  return fast_rcp(1.f + __expf(-x));
}

// ---------------- weight pre-pack (unchanged layouts) ----------------
__global__ void pack_weights(const float* __restrict__ W_d_w,
                             const float* __restrict__ W_hh,
                             const float* __restrict__ W_dec_w,
                             const float* __restrict__ W_y_w,
                             const float* __restrict__ U_d_w,
                             const float* __restrict__ w_tilda_w,
                             short* __restrict__ WdP, short* __restrict__ WhhP,
                             short* __restrict__ WdecP, u32* __restrict__ UdP,
                             u32* __restrict__ wtP, u32* __restrict__ WyP2) {
  const int i0 = blockIdx.x * blockDim.x + threadIdx.x;
  const int stride = gridDim.x * blockDim.x;
  for (int i = i0; i < 32768; i += stride) {  // WdP
    int e = i & 7, lane = (i >> 3) & 63, w = (i >> 9) & 7, kk = i >> 12;
    int n = w * 16 + (lane & 15), k = kk * 32 + (lane >> 4) * 8 + e;
    WdP[i] = (short)bfq(W_d_w[n * 256 + k]);
  }
  for (int i = i0; i < 65536; i += stride) {  // WhhP
    int e = i & 7, lane = (i >> 3) & 63, nt = (i >> 9) & 31, kk = i >> 14;
    int n = nt * 16 + (lane & 15), k = kk * 32 + (lane >> 4) * 8 + e;
    WhhP[i] = (short)bfq(W_hh[n * 128 + k]);
  }
  for (int i = i0; i < 1064960; i += stride) {  // WdecP (blocks 0..64)
    int e = i & 7, lane = (i >> 3) & 63, w = (i >> 9) & 7, kk = (i >> 12) & 3, tt = i >> 14;
    int n = w * 16 + (lane & 15), k = kk * 32 + (lane >> 4) * 8 + e;
    WdecP[i] = (short)bfq(W_dec_w[n * 8320 + tt * 128 + k]);
  }
  for (int i = i0; i < 8192; i += stride) {  // UdP [k2<64][m<128] f16 pairs
    int m = i & 127, k2 = i >> 7;
    UdP[i] = pkh(U_d_w[m * 128 + 2 * k2], U_d_w[m * 128 + 2 * k2 + 1]);
  }
  for (int i = i0; i < 64; i += stride)  // wtP
    wtP[i] = pkh(w_tilda_w[2 * i], w_tilda_w[2 * i + 1]);
  for (int i = i0; i < 16384; i += stride) {  // WyP2
    int jj = i & 63, k = i >> 6;
    WyP2[i] = pkh(W_y_w[(2 * jj) * 256 + k], W_y_w[(2 * jj + 1) * 256 + k]);
  }
}

// ---------------- fused scan ----------------
// LDS (bytes), STATIC:
//   E     u32 [p<32][r<16][l<64]  @ 0       (131072)  E=exp2(CE*y1) pairs 0-31
//   cat   u32 [16][132]           @ 131072  (8448)
//   x1h   f16 [16][128]           @ 139520  (4096)    X = exp2(CE*x1)
//   gth   f16 [16][512]           @ 143616  (16384)   gates
//   va2   f32 [128]               @ 160000  (512)
//   wih_s f32 [512]               @ 160512  (2048)
//   ---- epilogue aliases (E dead): beta @ 0 (4096), cat2 @ 4096 (16384)
#define LDS_BYTES 162560

#define CHUNK_CORE(C)                                                          \
    f32x4 a0 = {0, 0, 0, 0}, a1 = {0, 0, 0, 0};                                \
    for (int k2 = 0; k2 < 64; ++k2) {                                          \
      float2 ev = *(const float2*)(enc_row + 2 * k2);                          \
      u32 ep = pkh(ev.x, ev.y);                                                \
      const uint4* uvp = UdP4 + k2 * 32 + (C) * 2;                             \
      uint4 u0 = uvp[0], u1 = uvp[1];                                          \
      a0.x = dot2h(ep, u0.x, a0.x); a0.y = dot2h(ep, u0.y, a0.y);              \
      a0.z = dot2h(ep, u0.z, a0.z); a0.w = dot2h(ep, u0.w, a0.w);              \
      a1.x = dot2h(ep, u1.x, a1.x); a1.y = dot2h(ep, u1.y, a1.y);              \
      a1.z = dot2h(ep, u1.z, a1.z); a1.w = dot2h(ep, u1.w, a1.w);              \
    }

#define CHUNK_LDS(C)                                                           \
  do {                                                                         \
    CHUNK_CORE(C)                                                              \
    u32* yb = E + ((C) * 4) * 1024 + wv * 64 + lane;                           \
    yb[0]    = pkh(FEXP(CE * a0.x), FEXP(CE * a0.y));                          \
    yb[1024] = pkh(FEXP(CE * a0.z), FEXP(CE * a0.w));                          \
    yb[2048] = pkh(FEXP(CE * a1.x), FEXP(CE * a1.y));                          \
    yb[3072] = pkh(FEXP(CE * a1.z), FEXP(CE * a1.w));                          \
  } while (0)

#define CHUNK_REG(C, OUT)                                                      \
  do {                                                                         \
    CHUNK_CORE(C)                                                              \
    OUT = make_uint4(pkh(FEXP(CE * a0.x), FEXP(CE * a0.y)),                    \
                     pkh(FEXP(CE * a0.z), FEXP(CE * a0.w)),                    \
                     pkh(FEXP(CE * a1.x), FEXP(CE * a1.y)),                    \
                     pkh(FEXP(CE * a1.z), FEXP(CE * a1.w)));                   \
  } while (0)

#define CHUNK_GLB(C)                                                           \
  do {                                                                         \
    CHUNK_CORE(C)                                                              \
    Eg4[(((C) - 8) * 16 + wv) * 64 + lane] =                                   \
        make_uint4(pkh(FEXP(CE * a0.x), FEXP(CE * a0.y)),                      \
                   pkh(FEXP(CE * a0.z), FEXP(CE * a0.w)),                      \
                   pkh(FEXP(CE * a1.x), FEXP(CE * a1.y)),                      \
                   pkh(FEXP(CE * a1.z), FEXP(CE * a1.w)));                     \
  } while (0)

// logit group core: 4 E-pairs, 4 X-pairs (f16), 8 va values
#define QCORE(Y0, Y1, Y2, Y3, G)                                               \
  {                                                                            \
    const u32* xp = (const u32*)(x1h + wv * 128 + (G) * 8);                    \
    u32 X0 = xp[0], X1 = xp[1], X2 = xp[2], X3 = xp[3];                        \
    float4 va = *(const float4*)(va2 + (G) * 8);                               \
    float4 vb = *(const float4*)(va2 + (G) * 8 + 4);                           \
    h2 e, x;                                                                   \
    e = as_h2(Y0); x = as_h2(X0);                                              \
    q0 = fmaf(va.x, fast_rcp(fmaf((float)e.x, (float)x.x, 1.f)), q0);          \
    q1 = fmaf(va.y, fast_rcp(fmaf((float)e.y, (float)x.y, 1.f)), q1);          \
    e = as_h2(Y1); x = as_h2(X1);                                              \
    q2 = fmaf(va.z, fast_rcp(fmaf((float)e.x, (float)x.x, 1.f)), q2);          \
    q3 = fmaf(va.w, fast_rcp(fmaf((float)e.y, (float)x.y, 1.f)), q3);          \
    e = as_h2(Y2); x = as_h2(X2);                                              \
    q0 = fmaf(vb.x, fast_rcp(fmaf((float)e.x, (float)x.x, 1.f)), q0);          \
    q1 = fmaf(vb.y, fast_rcp(fmaf((float)e.y, (float)x.y, 1.f)), q1);          \
    e = as_h2(Y3); x = as_h2(X3);                                              \
    q2 = fmaf(vb.z, fast_rcp(fmaf((float)e.x, (float)x.x, 1.f)), q2);          \
    q3 = fmaf(vb.w, fast_rcp(fmaf((float)e.y, (float)x.y, 1.f)), q3);          \
  }

#define QGROUP_L(G)                                                            \
  {                                                                            \
    const u32* Eb = E + (G) * 4 * 1024 + wv * 64 + lane;                       \
    QCORE(Eb[0], Eb[1024], Eb[2048], Eb[3072], G)                              \
  }
#define QGROUP_R(G, Y) QCORE((Y).x, (Y).y, (Y).z, (Y).w, G)

#define AFRAG(KK) (*(const s16x8*)(cat_u + arow + (KK) * 16))

template <int GLOBE>
__global__ __launch_bounds__(NTH)
__attribute__((amdgpu_waves_per_eu(4, 4)))
void fused_main(
    const float* __restrict__ enc, const float* __restrict__ y,
    const float* __restrict__ W_d_b, const float* __restrict__ v_d_w,
    const float* __restrict__ w_tilda_w, const float* __restrict__ w_tilda_b,
    const float* __restrict__ W_ih, const float* __restrict__ b_ih,
    const float* __restrict__ b_hh, const float* __restrict__ W_dec_b,
    const float* __restrict__ W_y_b, const float* __restrict__ v_y_w,
    const float* __restrict__ v_y_b,
    const short* __restrict__ WdP, const short* __restrict__ WhhP,
    const short* __restrict__ WdecP, const uint4* __restrict__ UdP4,
    const u32* __restrict__ wtP, const u32* __restrict__ WyP2,
    uint4* __restrict__ EgBase, float* __restrict__ out) {
  __shared__ char lds[LDS_BYTES];
  u32* E = (u32*)lds;
  u32* cat_u = (u32*)(lds + 131072);
  _Float16* x1h = (_Float16*)(lds + 139520);
  _Float16* gth = (_Float16*)(lds + 143616);
  float* va2 = (float*)(lds + 160000);
  float* wih_s = (float*)(lds + 160512);
  float* beta_s = (float*)lds;           // epilogue alias (E dead)
  float* cat2 = (float*)(lds + 4096);    // epilogue alias (E dead)

  const int tid = threadIdx.x;
  const int lane = tid & 63;
  const int wv = tid >> 6;   // 0..15 == batch row
  const int b = blockIdx.x * NB + wv;
  const int j = lane;
  uint4* Eg4 = EgBase + (size_t)blockIdx.x * (8 * 16 * 64);

  for (int i = tid; i < 16 * 132; i += NTH) cat_u[i] = 0u;
  if (wv == 0) {
    va2[lane] = 2.f * v_d_w[lane];
    va2[64 + lane] = 2.f * v_d_w[64 + lane];
  }
  for (int i = tid; i < 512; i += NTH) wih_s[i] = W_ih[i];

  // ---- phase 0: E for own row -> 32 pairs LDS + 32 pairs (regs | global) ----
  const float* enc_row = enc + ((size_t)b * 64 + lane) * 128;
  float ew = 0.f;
  for (int k2 = 0; k2 < 64; ++k2) {
    float2 ev = *(const float2*)(enc_row + 2 * k2);
    ew = dot2h(pkh(ev.x, ev.y), wtP[k2], ew);
  }
  CHUNK_LDS(0); CHUNK_LDS(1); CHUNK_LDS(2); CHUNK_LDS(3);
  CHUNK_LDS(4); CHUNK_LDS(5); CHUNK_LDS(6); CHUNK_LDS(7);
  uint4 Yr0, Yr1, Yr2, Yr3, Yr4, Yr5, Yr6, Yr7;
  if constexpr (GLOBE) {
    CHUNK_GLB(8);  CHUNK_GLB(9);  CHUNK_GLB(10); CHUNK_GLB(11);
    CHUNK_GLB(12); CHUNK_GLB(13); CHUNK_GLB(14); CHUNK_GLB(15);
  } else {
    CHUNK_REG(8, Yr0);  CHUNK_REG(9, Yr1);  CHUNK_REG(10, Yr2); CHUNK_REG(11, Yr3);
    CHUNK_REG(12, Yr4); CHUNK_REG(13, Yr5); CHUNK_REG(14, Yr6); CHUNK_REG(15, Yr7);
  }

  const float wt_y = w_tilda_w[128];
  const float wt_b0 = w_tilda_b[0];
  float svv = v_d_w[lane] + v_d_w[64 + lane];
#pragma unroll
  for (int off = 32; off; off >>= 1) svv += __shfl_xor(svv, off, 64);
  const float sv = __int_as_float(__builtin_amdgcn_readfirstlane(__float_as_int(svv)));

  const int ccol = lane & 15;
  const int crow = (lane >> 4) * 4;
  const int arow = ccol * 132 + (lane >> 4) * 4;
  const float wdb_n = W_d_b[(wv & 7) * 16 + ccol];
  const float dfb_n = W_dec_b[(wv & 7) * 16 + ccol];
  const float bini0 = b_ih[wv * 32 + ccol] + b_hh[wv * 32 + ccol];
  const float bini1 = b_ih[wv * 32 + 16 + ccol] + b_hh[wv * 32 + 16 + ccol];
  f32x4 dfacc = {dfb_n, dfb_n, dfb_n, dfb_n};
  float s0 = 0.f, s1 = 0.f, beta_sv = 0.f;

  __syncthreads();

#pragma unroll 1
  for (int t = 0; t < Tn; ++t) {
    // ---- phase A: GEMMs on matrix pipe ----
    if (wv < 8) {
      f32x4 c1 = {wdb_n, wdb_n, wdb_n, wdb_n};
#pragma unroll
      for (int kk = 0; kk < 8; ++kk) {
        s16x8 bf = *(const s16x8*)(WdP + (((kk * 8 + wv) * 64 + lane) * 8));
        c1 = MFMA16(AFRAG(kk), bf, c1);
      }
#pragma unroll
      for (int r4 = 0; r4 < 4; ++r4)
        x1h[(crow + r4) * 128 + wv * 16 + ccol] = (_Float16)FEXP(c1[r4] * CE);
    } else {
      const int w8 = wv - 8;
#pragma unroll
      for (int kk = 0; kk < 4; ++kk) {
        s16x8 bf = *(const s16x8*)(WdecP + ((((t * 4 + kk) * 8 + w8) * 64 + lane) * 8));
        dfacc = MFMA16(AFRAG(kk), bf, dfacc);
      }
    }
#pragma unroll
    for (int it = 0; it < 2; ++it) {
      const float bini = it ? bini1 : bini0;
      f32x4 c2 = {bini, bini, bini, bini};
      const int nt = wv * 2 + it;
#pragma unroll
      for (int kk = 0; kk < 4; ++kk) {
        s16x8 bf = *(const s16x8*)(WhhP + (((kk * 32 + nt) * 64 + lane) * 8));
        c2 = MFMA16(AFRAG(kk), bf, c2);
      }
#pragma unroll
      for (int r4 = 0; r4 < 4; ++r4)
        gth[(crow + r4) * 512 + nt * 16 + ccol] = (_Float16)c2[r4];
    }
    __syncthreads();

    // ---- phase B: full logits for own row ----
    float q0 = 0.f, q1 = 0.f, q2 = 0.f, q3 = 0.f;
    if constexpr (GLOBE) {
      // issue first global E batch early; hide under LDS-half QGROUPs
      uint4 eA0 = Eg4[(0 * 16 + wv) * 64 + lane];
      uint4 eA1 = Eg4[(1 * 16 + wv) * 64 + lane];
      uint4 eA2 = Eg4[(2 * 16 + wv) * 64 + lane];
      uint4 eA3 = Eg4[(3 * 16 + wv) * 64 + lane];
      QGROUP_L(0) QGROUP_L(1) QGROUP_L(2) QGROUP_L(3)
      QGROUP_L(4) QGROUP_L(5) QGROUP_L(6) QGROUP_L(7)
      uint4 eB0 = Eg4[(4 * 16 + wv) * 64 + lane];
      uint4 eB1 = Eg4[(5 * 16 + wv) * 64 + lane];
      uint4 eB2 = Eg4[(6 * 16 + wv) * 64 + lane];
      uint4 eB3 = Eg4[(7 * 16 + wv) * 64 + lane];
      QGROUP_R(8, eA0)  QGROUP_R(9, eA1)  QGROUP_R(10, eA2) QGROUP_R(11, eA3)
      QGROUP_R(12, eB0) QGROUP_R(13, eB1) QGROUP_R(14, eB2) QGROUP_R(15, eB3)
    } else {
      QGROUP_L(0) QGROUP_L(1) QGROUP_L(2) QGROUP_L(3)
      QGROUP_L(4) QGROUP_L(5) QGROUP_L(6) QGROUP_L(7)
      QGROUP_R(8, Yr0)  QGROUP_R(9, Yr1)  QGROUP_R(10, Yr2) QGROUP_R(11, Yr3)
      QGROUP_R(12, Yr4) QGROUP_R(13, Yr5) QGROUP_R(14, Yr6) QGROUP_R(15, Yr7)
    }
    float lg = sv - (q0 + q1 + q2 + q3);
    float pexp = __expf(lg);  // |lg| bounded ~15: no max pass needed
    float smv = pexp, yt = pexp * ew;
#pragma unroll
    for (int off = 32; off; off >>= 1) {
      smv += __shfl_xor(smv, off, 64);
      yt += __shfl_xor(yt, off, 64);
    }
    float rs = fast_rcp(smv);
    if (t == Tn - 1) beta_sv = pexp * rs;
    float ytil = yt * rs + y[(size_t)b * 64 + t] * wt_y + wt_b0;

    const u32* gp = (const u32*)(gth + wv * 512 + 2 * j);
    h2 pgi = as_h2(gp[0]);
    h2 pgf = as_h2(gp[64]);
    h2 pgg = as_h2(gp[128]);
    h2 pgo = as_h2(gp[192]);
    float2 wi0 = *(const float2*)(wih_s + 2 * j);
    float2 wi1 = *(const float2*)(wih_s + 128 + 2 * j);
    float2 wi2 = *(const float2*)(wih_s + 256 + 2 * j);
    float2 wi3 = *(const float2*)(wih_s + 384 + 2 * j);
    float i0 = fast_sig((float)pgi.x + ytil * wi0.x);
    float i1 = fast_sig((float)pgi.y + ytil * wi0.y);
    float f0 = fast_sig((float)pgf.x + ytil * wi1.x);
    float f1 = fast_sig((float)pgf.y + ytil * wi1.y);
    float g0 = fast_tanh((float)pgg.x + ytil * wi2.x);
    float g1 = fast_tanh((float)pgg.y + ytil * wi2.y);
    float o0 = fast_sig((float)pgo.x + ytil * wi3.x);
    float o1 = fast_sig((float)pgo.y + ytil * wi3.y);
    s0 = f0 * s0 + i0 * g0;
    s1 = f1 * s1 + i1 * g1;
    float d0 = o0 * fast_tanh(s0);
    float d1 = o1 * fast_tanh(s1);
    cat_u[wv * 132 + j] = pack2bf(d0, d1);
    cat_u[wv * 132 + 64 + j] = pack2bf(s0, s1);
    __syncthreads();
  }

  // ---- epilogue (E dead; beta/cat2 alias it) ----
  beta_s[wv * 64 + lane] = beta_sv;
  if (wv >= 8) {  // finish d_fin with Wdec block 64
    const int w8 = wv - 8;
#pragma unroll
    for (int kk = 0; kk < 4; ++kk) {
      s16x8 bf = *(const s16x8*)(WdecP + ((((64 * 4 + kk) * 8 + w8) * 64 + lane) * 8));
      dfacc = MFMA16(AFRAG(kk), bf, dfacc);
    }
#pragma unroll
    for (int r4 = 0; r4 < 4; ++r4)
      cat2[(crow + r4) * 256 + w8 * 16 + ccol] = dfacc[r4];
  }
  __syncthreads();

  // c_T for own row
  float c0 = 0.f, c1v = 0.f;
#pragma unroll 2
  for (int it = 0; it < 16; ++it) {
    float4 bv = *(const float4*)(beta_s + wv * 64 + it * 4);
    float2 e0 = *(const float2*)(enc + ((size_t)b * 64 + it * 4 + 0) * 128 + 2 * j);
    float2 e1 = *(const float2*)(enc + ((size_t)b * 64 + it * 4 + 1) * 128 + 2 * j);
    float2 e2 = *(const float2*)(enc + ((size_t)b * 64 + it * 4 + 2) * 128 + 2 * j);
    float2 e3 = *(const float2*)(enc + ((size_t)b * 64 + it * 4 + 3) * 128 + 2 * j);
    c0 = fmaf(bv.x, e0.x, c0); c1v = fmaf(bv.x, e0.y, c1v);
    c0 = fmaf(bv.y, e1.x, c0); c1v = fmaf(bv.y, e1.y, c1v);
    c0 = fmaf(bv.z, e2.x, c0); c1v = fmaf(bv.z, e2.y, c1v);
    c0 = fmaf(bv.w, e3.x, c0); c1v = fmaf(bv.w, e3.y, c1v);
  }
  *(float2*)(cat2 + wv * 256 + 128 + 2 * j) = make_float2(c0, c1v);

  // final head for own row
  float2 hb = *(const float2*)(W_y_b + 2 * j);
  float h0v = hb.x, h1v = hb.y;
#pragma unroll 4
  for (int it = 0; it < 64; ++it) {
    float4 cv = *(const float4*)(cat2 + wv * 256 + it * 4);
    u32 w0 = WyP2[(it * 4 + 0) * 64 + j];
    u32 w1 = WyP2[(it * 4 + 1) * 64 + j];
    u32 w2 = WyP2[(it * 4 + 2) * 64 + j];
    u32 w3 = WyP2[(it * 4 + 3) * 64 + j];
    h2 p0 = as_h2(w0), p1 = as_h2(w1), p2 = as_h2(w2), p3 = as_h2(w3);
    h0v = fmaf(cv.x, (float)p0.x, h0v); h1v = fmaf(cv.x, (float)p0.y, h1v);
    h0v = fmaf(cv.y, (float)p1.x, h0v); h1v = fmaf(cv.y, (float)p1.y, h1v);
    h0v = fmaf(cv.z, (float)p2.x, h0v); h1v = fmaf(cv.z, (float)p2.y, h1v);
    h0v = fmaf(cv.w, (float)p3.x, h0v); h1v = fmaf(cv.w, (float)p3.y, h1v);
  }
  float2 vy = *(const float2*)(v_y_w + 2 * j);
  float rsum = h0v * vy.x + h1v * vy.y;
#pragma unroll
  for (int off = 32; off; off >>= 1) rsum += __shfl_xor(rsum, off, 64);
  if (lane == 0) out[b] = rsum + v_y_b[0];
}

extern "C" void kernel_launch(void* const* d_in, const int* in_sizes, int n_in,
                              void* d_out, int out_size, void* d_ws, size_t ws_size,
                              hipStream_t stream) {
  const float* enc = (const float*)d_in[0];
  const float* y = (const float*)d_in[1];
  const float* W_d_w = (const float*)d_in[2];
  const float* W_d_b = (const float*)d_in[3];
  const float* U_d_w = (const float*)d_in[4];
  const float* v_d_w = (const float*)d_in[5];
  const float* w_tilda_w = (const float*)d_in[6];
  const float* w_tilda_b = (const float*)d_in[7];
  const float* W_ih = (const float*)d_in[8];
  const float* b_ih = (const float*)d_in[9];
  const float* W_hh = (const float*)d_in[10];
  const float* b_hh = (const float*)d_in[11];
  const float* W_dec_w = (const float*)d_in[12];
  const float* W_dec_b = (const float*)d_in[13];
  const float* W_y_w = (const float*)d_in[14];
  const float* W_y_b = (const float*)d_in[15];
  const float* v_y_w = (const float*)d_in[16];
  const float* v_y_b = (const float*)d_in[17];

  char* ws = (char*)d_ws;
  short* WdP = (short*)(ws + 0);
  short* WhhP = (short*)(ws + 65536);
  short* WdecP = (short*)(ws + 196608);
  u32* UdP = (u32*)(ws + 2326528);
  u32* wtP = (u32*)(ws + 2359296);
  u32* WyP2 = (u32*)(ws + 2359552);
  uint4* Eg = (uint4*)(ws + 4194304);  // 256 blocks * 128 KB = 33.5 MB
  const size_t need = 4194304ull + (size_t)(4096 / NB) * 8 * 16 * 64 * 16;

  pack_weights<<<512, 256, 0, stream>>>(W_d_w, W_hh, W_dec_w, W_y_w, U_d_w,
                                        w_tilda_w, WdP, WhhP, WdecP, UdP, wtP, WyP2);
  if (ws_size >= need) {
    fused_main<1><<<4096 / NB, NTH, 0, stream>>>(
        enc, y, W_d_b, v_d_w, w_tilda_w, w_tilda_b, W_ih, b_ih, b_hh, W_dec_b,
        W_y_b, v_y_w, v_y_b, WdP, WhhP, WdecP, (const uint4*)UdP, wtP, WyP2,
        Eg, (float*)d_out);
  } else {
    fused_main<0><<<4096 / NB, NTH, 0, stream>>>(
        enc, y, W_d_b, v_d_w, w_tilda_w, w_tilda_b, W_ih, b_ih, b_hh, W_dec_b,
        W_y_b, v_y_w, v_y_b, WdP, WhhP, WdecP, (const uint4*)UdP, wtP, WyP2,
        Eg, (float*)d_out);
  }
}